// Round 4
// baseline (871.096 us; speedup 1.0000x reference)
//
#include <hip/hip_runtime.h>
#include <hip/hip_bf16.h>

// GGNN encoder: N=10000, H=512, T=4, E=40000, L=2 x 2 timesteps.
// fp32 inputs, fp32 output, bf16 MFMA internally.
//
// Per step (2 GEMM dispatches):
//   Msg  = h @ Wmsg_cat^T              (N x 2048, K=512)   [MODE 0]
//   inc  = gather-sum(Msg) + cnt*b     (N x 512)           [gather_msum]
//   h'   = fused GRU GEMM: [inc|h] @ Wrznh^T with GATE-INTERLEAVED packing
//          + in-register sigmoid/tanh/blend epilogue -> h32 (f32) + h (bf16)
//          [MODE 1]
// Final: FC + column-max fused [MODE 3] -> writeout.
//
// r15 change (single lever): BARRIER-FREE per-wave GEMM.
//   r14 still had 2 workgroup barriers per K-iter; with ~1.4 resident
//   blocks (LDS=48KB) every exposed latency stalled all 4 waves in
//   lockstep (~2200 cyc/block-iter vs ~300 cyc content; Mfma 17%).
//   Now each wave loads its A fragments DIRECTLY global->register at the
//   exact MFMA fragment addresses (per (i,s): 16 rows x 64 consecutive
//   bytes -- full 64B cache lines), B as before. No LDS staging, no
//   global_load_lds, NO barriers in the main loop; waves slip freely.
//   Depth-2 ping-pong on both A and B (16 loads in flight, vmcnt(16)).
//   LDS shrinks to a 17KB epilogue scratch (occupancy no longer
//   LDS-bound); VGPR rises (~220) under __launch_bounds__(256,2).
//
// Carried from r12-r14: fused GRU epilogue (gate-interleaved WrznhPK,
// per-kt j-skip), XCD-aware swizzle (bcol fastest per XCD), packed
// fragment-order weights.

#define NN 10000
#define HD 512
#define NT 4
#define NE 40000
#define CAP 24          // max edges per (target,type); P(Poisson(4)>24)~1e-14/bin
#define GYROWS 80       // padded to multiple of 8 for XCD swizzle (79 used)

typedef __bf16 bf16x8 __attribute__((ext_vector_type(8)));
typedef float f32x4 __attribute__((ext_vector_type(4)));
union V16 { int4 i; bf16x8 b; };

__device__ __forceinline__ float bfl(__bf16 v) { return (float)v; }

// pack 8 fp32 -> int4 of 8 bf16
__device__ __forceinline__ int4 cvt8(const float* __restrict__ s) {
    float4 v0 = *(const float4*)s, v1 = *(const float4*)(s + 4);
    V16 o;
    o.b[0] = (__bf16)v0.x; o.b[1] = (__bf16)v0.y; o.b[2] = (__bf16)v0.z; o.b[3] = (__bf16)v0.w;
    o.b[4] = (__bf16)v1.x; o.b[5] = (__bf16)v1.y; o.b[6] = (__bf16)v1.z; o.b[7] = (__bf16)v1.w;
    return o.i;
}

// Packed-W layout: [ct][kt32][s], s=0..511: wc=s>>8, j=(s>>6)&3, lane=s&63.
// Entry = int4 of W[pc][kt32*32+quad*8 .. +8], pc = ct*128+wc*64+j*16+(lane&15).
__device__ __forceinline__ void pk_decode(int rem, int KTbits, int& col, int& kk) {
    int ct = rem >> (KTbits + 9);
    int r2 = rem & ((1 << (KTbits + 9)) - 1);
    int kt = r2 >> 9, s = r2 & 511;
    int lane = s & 63;
    col = ct * 128 + ((s >> 8) << 6) + (((s >> 6) & 3) << 4) + (lane & 15);
    kk = kt * 32 + ((lane >> 4) & 3) * 8;
}

// ---------------- fused prep: pack weights, init, bins ----------------------
__global__ void prep_all(const float* __restrict__ Wmsg, const float* __restrict__ Wih,
                         const float* __restrict__ Whh, const float* __restrict__ fcW,
                         const float* __restrict__ x, const int* __restrict__ edges,
                         int4* __restrict__ WmPK, int4* __restrict__ WrznhPK,
                         int4* __restrict__ WfPK,
                         float* __restrict__ h32, __hip_bfloat16* __restrict__ ab,
                         int* __restrict__ bcnt, int* __restrict__ bins) {
    int blk = blockIdx.x, tid = threadIdx.x;
    if (blk < 1024) {            // WmPK: per layer 16ct x 16kt x 512 = 131072
        int g = blk * 256 + tid;
        int l = g >> 17, rem = g & 131071;
        int col, kk; pk_decode(rem, 4, col, kk);
        WmPK[g] = cvt8(Wmsg + (size_t)l * 1048576 + (size_t)col * 512 + kk);
        return;
    }
    blk -= 1024;
    if (blk < 2048) {            // WrznhPK: per layer 16ct x 32kt x 512 = 262144
        // GATE-INTERLEAVED: packed col pc -> gate g=(pc>>4)&3,
        // hcol = (bcol*2 + wc)*16 + lm, bcol=pc>>7, wc=(pc>>6)&1, lm=pc&15.
        int g = blk * 256 + tid;
        int l = g >> 18, rem = g & 262143;
        int col, kk; pk_decode(rem, 5, col, kk);
        int gate = (col >> 4) & 3;
        int hcol = ((col >> 7) * 2 + ((col >> 6) & 1)) * 16 + (col & 15);
        int4 v = make_int4(0, 0, 0, 0);
        if (kk < 512) {
            // inc-half: W_ih rows {r:hcol, z:512+hcol, i_n:1024+hcol}; hn=0
            if (gate < 3) v = cvt8(Wih + (size_t)l * 786432 + (size_t)(gate * 512 + hcol) * 512 + kk);
        } else {
            // h-half: W_hh rows {r:hcol, z:512+hcol, hn:1024+hcol}; i_n=0
            if (gate < 2) v = cvt8(Whh + (size_t)l * 786432 + (size_t)(gate * 512 + hcol) * 512 + (kk - 512));
            else if (gate == 3) v = cvt8(Whh + (size_t)l * 786432 + (size_t)(1024 + hcol) * 512 + (kk - 512));
        }
        WrznhPK[g] = v;
        return;
    }
    blk -= 2048;
    if (blk < 128) {             // WfPK: 4ct x 16kt x 512 = 32768
        int g = blk * 256 + tid;
        int col, kk; pk_decode(g, 4, col, kk);
        WfPK[g] = cvt8(fcW + (size_t)col * 512 + kk);
        return;
    }
    blk -= 128;
    if (blk < 5000) {            // init: h32 <- x, abA h-slot <- bf16(x)
        int i = blk * 1024 + tid * 4;
        float4 v = *(const float4*)(x + i);
        *(float4*)(h32 + i) = v;
        int m = i >> 9, c = i & 511;
        __hip_bfloat16 o[4] = {__float2bfloat16(v.x), __float2bfloat16(v.y),
                               __float2bfloat16(v.z), __float2bfloat16(v.w)};
        *(ulong1*)(ab + (size_t)m * 1024 + 512 + c) = *(ulong1*)o;
        return;
    }
    blk -= 5000;
    {                            // build_bins
        int i = blk * 256 + tid;
        if (i >= NT * NE) return;
        int src = edges[2 * i], tgt = edges[2 * i + 1];
        int t = i / NE;
        int b = tgt * NT + t;
        int pos = atomicAdd(&bcnt[b], 1);
        if (pos < CAP) bins[(size_t)b * CAP + pos] = src;
    }
}

// ---------------- gather: inc[n][c] = sum_t sum_src Msg[src][t*512+c] + cnt*bm
__global__ __launch_bounds__(256) void gather_msum(
    const int* __restrict__ bins, const int* __restrict__ bcnt,
    const float* __restrict__ bm, const __hip_bfloat16* __restrict__ Msg,
    __hip_bfloat16* __restrict__ inc) {
    int wave = threadIdx.x >> 6, lane = threadIdx.x & 63;
    int n = blockIdx.x * 4 + wave;
    int co = lane * 8;
    float acc[8] = {0, 0, 0, 0, 0, 0, 0, 0};
#pragma unroll
    for (int t = 0; t < NT; ++t) {
        int bi = n * NT + t;
        int cnt = bcnt[bi]; if (cnt > CAP) cnt = CAP;
        const int* bl = bins + (size_t)bi * CAP;
        for (int e = 0; e < cnt; ++e) {
            int src = bl[e];
            V16 v; v.i = *(const int4*)(Msg + (size_t)src * 2048 + t * 512 + co);
#pragma unroll
            for (int k = 0; k < 8; ++k) acc[k] += (float)v.b[k];
        }
        float4 b0 = *(const float4*)(bm + t * 512 + co);
        float4 b1 = *(const float4*)(bm + t * 512 + co + 4);
        float fc = (float)cnt;
        acc[0] += fc * b0.x; acc[1] += fc * b0.y; acc[2] += fc * b0.z; acc[3] += fc * b0.w;
        acc[4] += fc * b1.x; acc[5] += fc * b1.y; acc[6] += fc * b1.z; acc[7] += fc * b1.w;
    }
    V16 o;
#pragma unroll
    for (int k = 0; k < 8; ++k) o.b[k] = (__bf16)acc[k];
    *(int4*)(inc + (size_t)n * 1024 + co) = o.i;
}

// ---------------- monotone-uint float max encoding ----------------
__device__ __forceinline__ unsigned fenc(float f) {
    unsigned b = __float_as_uint(f);
    return b ^ (((int)b >> 31) | 0x80000000u);
}
__device__ __forceinline__ float fdec(unsigned u) {
    unsigned b = (u & 0x80000000u) ? (u ^ 0x80000000u) : ~u;
    return __uint_as_float(b);
}

// ---------------- GEMM: out = A(NNxK,lda) @ W^T, 128x128 tile, BK=64 ---------
// BARRIER-FREE: each wave computes its own 64x64 (wr,wc) sub-tile with
// per-lane direct global->register A loads at the MFMA fragment layout,
// ping-pong depth-2 on A and B, vmcnt(16) per iteration. No main-loop LDS.
template<int MODE>
__global__ __launch_bounds__(256, 2) void gemm(
    const __hip_bfloat16* __restrict__ A, int lda, int K,
    const int4* __restrict__ Wpk,
    const float* __restrict__ b0, const float* __restrict__ b1,
    __hip_bfloat16* __restrict__ obf, int ldo,
    float* __restrict__ h32, unsigned* __restrict__ om) {
    __shared__ float ldsF[128 * 33];          // 16.9 KB epilogue scratch
    __shared__ unsigned sm[128];
    __hip_bfloat16* lds = (__hip_bfloat16*)ldsF;  // MODE 0 epilogue view

    const int NB = (MODE == 3) ? 4 : 16;      // bcols in grid
    int bid = blockIdx.x;
    int xcd = bid & 7, kq = bid >> 3;
    int bcol = kq % NB;
    int brow = xcd + 8 * (kq / NB);           // 0..79 exactly covered
    int m0 = brow * 128, n0 = bcol * 128;

    int tid = threadIdx.x;
    int lane = tid & 63, wave = tid >> 6;
    int wr = wave >> 1, wc = wave & 1;
    int lm = lane & 15, quad = lane >> 4;

    const int KT32 = K >> 5;
    const int KT = K >> 6;       // BK64 tiles
    const int kend = KT;         // uniform (MODE 1 zero-structure handled per-j)
    const int4* Wp = Wpk + ((size_t)bcol * KT32 << 9) + wc * 256 + lane;

    // per-lane A row pointers for the 4 fragment rows this wave reads
    const __hip_bfloat16* Ar[4];
#pragma unroll
    for (int i = 0; i < 4; ++i) {
        int gm = m0 + wr * 64 + i * 16 + lm;
        gm = gm < NN ? gm : NN - 1;
        Ar[i] = A + (size_t)gm * lda + quad * 8;
    }

    auto loadA = [&](int kt, V16 (&aa)[4][2]) {
        int k0 = kt << 6;
#pragma unroll
        for (int i = 0; i < 4; ++i)
#pragma unroll
            for (int s = 0; s < 2; ++s)
                aa[i][s].i = *(const int4*)(Ar[i] + k0 + s * 32);
    };
    auto loadB = [&](int kt, int4 (&bb)[2][4]) {
#pragma unroll
        for (int s = 0; s < 2; ++s) {
            const int4* wn = Wp + ((size_t)(2 * kt + s) << 9);
#pragma unroll
            for (int j = 0; j < 4; ++j) bb[s][j] = wn[j * 64];
        }
    };

    f32x4 acc[4][4] = {};
    V16 a0[4][2], a1[4][2];
    int4 br0[2][4], br1[2][4];
    loadA(0, a0);
    loadB(0, br0);

    auto ktbody = [&](int kt, V16 (&aC)[4][2], V16 (&aN)[4][2],
                      int4 (&bC)[2][4], int4 (&bN)[2][4]) {
        if (kt + 1 < kend) { loadA(kt + 1, aN); loadB(kt + 1, bN); }
        __builtin_amdgcn_sched_barrier(0);
        if (kt + 1 < kend) __builtin_amdgcn_s_waitcnt(0x4F70);  // vmcnt(16)
        else               __builtin_amdgcn_s_waitcnt(0x0F70);  // vmcnt(0)
        __builtin_amdgcn_sched_barrier(0);
#pragma unroll
        for (int s = 0; s < 2; ++s)
#pragma unroll
            for (int i = 0; i < 4; ++i)
#pragma unroll
                for (int j = 0; j < 4; ++j) {
                    if (MODE == 1) {   // structural zeros: i_n no h-half, hn no inc-half
                        if (j == 2 && kt >= 8) continue;
                        if (j == 3 && kt < 8) continue;
                    }
                    V16 b; b.i = bC[s][j];
                    acc[i][j] = __builtin_amdgcn_mfma_f32_16x16x32_bf16(aC[i][s].b, b.b, acc[i][j], 0, 0, 0);
                }
    };

    for (int k2 = 0; k2 < kend; k2 += 2) {       // kend always even (8 or 16)
        ktbody(k2, a0, a1, br0, br1);
        ktbody(k2 + 1, a1, a0, br1, br0);
    }

    if (MODE == 0) {
        // LDS-transpose epilogue, 2 row-phases of 64x128 bf16 (coalesced stores)
#pragma unroll
        for (int ph = 0; ph < 2; ++ph) {
            if (wr == ph) {
#pragma unroll
                for (int j = 0; j < 4; ++j) {
                    int c = wc * 64 + j * 16 + lm;
#pragma unroll
                    for (int i = 0; i < 4; ++i)
#pragma unroll
                        for (int r = 0; r < 4; ++r)
                            lds[(i * 16 + quad * 4 + r) * 128 + c] = __float2bfloat16(acc[i][j][r]);
                }
            }
            __syncthreads();
#pragma unroll
            for (int q = 0; q < 4; ++q) {
                int idx = q * 256 + tid;
                int rl = idx >> 4, c16 = idx & 15;
                int m = m0 + ph * 64 + rl;
                if (m < NN)
                    *(int4*)(obf + (size_t)m * ldo + n0 + c16 * 8) =
                        *(const int4*)(lds + rl * 128 + c16 * 8);
            }
            __syncthreads();
        }
    } else if (MODE == 1) {
        // fused GRU: acc[i][0..3] = r,z,i_n,hn partial sums for the SAME 16
        // h-cols (hcol = bcol*32 + wc*16 + lm). All-fp32 gate math.
        int c32 = wc * 16 + lm;
        int hcol = bcol * 32 + c32;
        float rb = b0[hcol] + b1[hcol];
        float zb = b0[512 + hcol] + b1[512 + hcol];
        float ib = b0[1024 + hcol];
        float hb = b1[1024 + hcol];
#pragma unroll
        for (int i = 0; i < 4; ++i)
#pragma unroll
            for (int r = 0; r < 4; ++r) {
                int rloc = wr * 64 + i * 16 + quad * 4 + r;
                int m = m0 + rloc;
                float hp = 0.f;
                if (m < NN) hp = h32[(size_t)m * 512 + hcol];
                float rr = 1.f / (1.f + __expf(-(acc[i][0][r] + rb)));
                float zz = 1.f / (1.f + __expf(-(acc[i][1][r] + zb)));
                float nx = (acc[i][2][r] + ib) + rr * (acc[i][3][r] + hb);
                float n = 1.f - 2.f / (__expf(2.f * nx) + 1.f);
                ldsF[rloc * 33 + c32] = (1.f - zz) * n + zz * hp;
            }
        __syncthreads();
        // coalesced writeout: 128 rows x 32 cols, f32 (h32) + bf16 (next A)
#pragma unroll
        for (int q = 0; q < 4; ++q) {
            int idx = q * 256 + tid;              // 1024 float4-units
            int rl = idx >> 3, c4 = (idx & 7) * 4;
            int m = m0 + rl;
            if (m < NN) {
                const float* pf = ldsF + rl * 33 + c4;
                float4 v = make_float4(pf[0], pf[1], pf[2], pf[3]);
                *(float4*)(h32 + (size_t)m * 512 + bcol * 32 + c4) = v;
                __hip_bfloat16 ob[4] = {__float2bfloat16(v.x), __float2bfloat16(v.y),
                                        __float2bfloat16(v.z), __float2bfloat16(v.w)};
                *(ulong1*)(obf + (size_t)m * ldo + bcol * 32 + c4) = *(ulong1*)ob;
            }
        }
    } else {   // MODE 3: FC + column max
        if (tid < 128) sm[tid] = 0;
        __syncthreads();
#pragma unroll
        for (int j = 0; j < 4; ++j) {
            int c = wc * 64 + j * 16 + lm;
            float bias = b0[n0 + c];
            float mx = -INFINITY;
#pragma unroll
            for (int i = 0; i < 4; ++i) {
                int r0 = m0 + wr * 64 + i * 16 + quad * 4;
#pragma unroll
                for (int r = 0; r < 4; ++r) {
                    int m = r0 + r;
                    if (m < NN) mx = fmaxf(mx, acc[i][j][r] + bias);
                }
            }
            atomicMax(&sm[c], fenc(mx));
        }
        __syncthreads();
        if (tid < 128) atomicMax(&om[n0 + tid], sm[tid]);
    }
}

__global__ void writeout(const unsigned* __restrict__ om, float* __restrict__ o) {
    int c = threadIdx.x;
    o[c] = fdec(om[c]);
}

// ---------------- launch ----------------
extern "C" void kernel_launch(void* const* d_in, const int* in_sizes, int n_in,
                              void* d_out, int out_size, void* d_ws, size_t ws_size,
                              hipStream_t stream) {
    (void)in_sizes; (void)n_in; (void)out_size; (void)ws_size;
    const float* x    = (const float*)d_in[0];
    const int*   edges= (const int*)d_in[1];
    const float* Wmsg = (const float*)d_in[2];
    const float* bmsg = (const float*)d_in[3];
    const float* Wih  = (const float*)d_in[4];
    const float* Whh  = (const float*)d_in[5];
    const float* bih  = (const float*)d_in[6];
    const float* bhh  = (const float*)d_in[7];
    const float* fcW  = (const float*)d_in[8];
    const float* fcb  = (const float*)d_in[9];
    float* out = (float*)d_out;

    char* ws = (char*)d_ws;
    size_t off = 0;
    auto alloc = [&](size_t bytes) -> void* {
        void* p = ws + off; off += (bytes + 255) & ~(size_t)255; return p;
    };
    float*          h32  = (float*)alloc((size_t)NN * HD * 4);              // 20.5 MB
    __hip_bfloat16* abA  = (__hip_bfloat16*)alloc((size_t)NN * 1024 * 2);   // 20.5 MB
    __hip_bfloat16* abB  = (__hip_bfloat16*)alloc((size_t)NN * 1024 * 2);   // 20.5 MB
    int*            bcnt = (int*)alloc((size_t)NN * NT * 4);                // 160 KB
    int*            bins = (int*)alloc((size_t)NN * NT * CAP * 4);          // 3.8 MB
    unsigned*       om   = (unsigned*)alloc(HD * 4);
    int4*           WmPK   = (int4*)alloc((size_t)2 * 131072 * 16);         // 4.2 MB
    int4*           WrznhPK= (int4*)alloc((size_t)2 * 262144 * 16);         // 8.4 MB
    int4*           WfPK   = (int4*)alloc((size_t)32768 * 16);              // 0.5 MB
    __hip_bfloat16* Msg  = (__hip_bfloat16*)alloc((size_t)NN * 2048 * 2);   // 41 MB
    // total ~119.5 MB

    hipMemsetAsync(bcnt, 0, (size_t)NN * NT * 4, stream);
    hipMemsetAsync(om, 0, HD * 4, stream);
    prep_all<<<1024 + 2048 + 128 + 5000 + 625, 256, 0, stream>>>(
        Wmsg, Wih, Whh, fcW, x, edges, WmPK, WrznhPK, WfPK, h32, abA, bcnt, bins);

    for (int s = 0; s < 4; ++s) {
        int layer = s >> 1;
        __hip_bfloat16* cur = (s & 1) ? abB : abA;
        __hip_bfloat16* nxt = (s & 1) ? abA : abB;
        const int4* Wm = WmPK + (size_t)layer * 131072;
        const int4* Wz = WrznhPK + (size_t)layer * 262144;
        const float* bm = bmsg + (size_t)layer * 2048;
        const float* bi = bih + (size_t)layer * 1536;
        const float* bh = bhh + (size_t)layer * 1536;

        // Msg = h @ Wm^T  (out 2048, K=512)
        gemm<0><<<16 * GYROWS, 256, 0, stream>>>(cur + 512, 1024, 512, Wm,
            nullptr, nullptr, Msg, 2048, nullptr, nullptr);
        // inc = gather(Msg) + cnt*bm -> cur[0:512]
        gather_msum<<<NN / 4, 256, 0, stream>>>(bins, bcnt, bm, Msg, cur);
        // fused GRU GEMM -> h32 (f32) + nxt h-slot (bf16)
        gemm<1><<<16 * GYROWS, 256, 0, stream>>>(cur, 1024, 1024, Wz,
            bi, bh, nxt + 512, 1024, h32, nullptr);
    }
    // FC + column max (final h in abA h-slot after 4 steps)
    gemm<3><<<4 * GYROWS, 256, 0, stream>>>(abA + 512, 1024, 512, WfPK,
        fcb, nullptr, nullptr, 0, nullptr, om);
    writeout<<<1, 512, 0, stream>>>(om, out);
}

// Round 5
// 611.045 us; speedup vs baseline: 1.4256x; 1.4256x over previous
//
#include <hip/hip_runtime.h>
#include <hip/hip_bf16.h>

// GGNN encoder: N=10000, H=512, T=4, E=40000, L=2 x 2 timesteps.
// fp32 inputs, fp32 output, bf16 MFMA internally.
//
// Per step (2 GEMM dispatches):
//   Msg  = h @ Wmsg_cat^T              (N x 2048, K=512)   [MODE 0]
//   inc  = gather-sum(Msg) + cnt*b     (N x 512)           [gather_msum]
//   h'   = fused GRU GEMM: [inc|h] @ Wrznh^T with GATE-INTERLEAVED packing
//          + in-register sigmoid/tanh/blend epilogue -> h (bf16)  [MODE 1]
// Final: FC + column-max fused [MODE 3] -> writeout.
//
// r16: REVERT r15 (barrier-free reg-A loads scattered 16 lines/instr, -50%)
//      back to the r14 staged structure, plus ONE lever: eliminate h32.
//   Evidence: r14 counters show gemm0 (8 K-iters) == gemm1 (16 K-iters)
//   == ~74 us, both ~95 MB @ ~1.3 TB/s -> the gemms are effective-BW-bound,
//   not latency/MFMA-bound. WRITE_SIZE 30 MB == h32(20.5)+ab(10.2): the
//   fp32 h32 round-trip is 41 MB/step of HBM traffic. The bf16 h is already
//   in the GEMM's A operand (cur[m][512:1024], L2-hot) -- read the GRU
//   blend's h from there and delete h32 entirely (buffer, init, read, write).
//   Numerics: only the z*h blend term loses f32 h (h entered the GEMM as
//   bf16 anyway); absmax expected ~<=0.016.
//
// Carried from r12-r14: fused GRU epilogue (gate-interleaved WrznhPK,
// per-kt j-skip), XCD-aware swizzle (rows per XCD, bcol fastest), involutive
// LDS bank swizzle on A staging, BK=64, 3 rotating 16KB LDS bufs, true
// depth-2 pipeline (ping-pong B regs, vmcnt(24/20/8) ladder).

#define NN 10000
#define HD 512
#define NT 4
#define NE 40000
#define CAP 24          // max edges per (target,type); P(Poisson(4)>24)~1e-14/bin
#define GYROWS 80       // padded to multiple of 8 for XCD swizzle (79 used)

typedef __bf16 bf16x8 __attribute__((ext_vector_type(8)));
typedef float f32x4 __attribute__((ext_vector_type(4)));
union V16 { int4 i; bf16x8 b; };

typedef __attribute__((address_space(1))) const unsigned int gu32;
typedef __attribute__((address_space(3))) unsigned int lu32;
__device__ __forceinline__ void gll16(const void* g, void* l) {
    __builtin_amdgcn_global_load_lds((gu32*)g, (lu32*)l, 16, 0, 0);
}

__device__ __forceinline__ float bfl(__bf16 v) { return (float)v; }

// pack 8 fp32 -> int4 of 8 bf16
__device__ __forceinline__ int4 cvt8(const float* __restrict__ s) {
    float4 v0 = *(const float4*)s, v1 = *(const float4*)(s + 4);
    V16 o;
    o.b[0] = (__bf16)v0.x; o.b[1] = (__bf16)v0.y; o.b[2] = (__bf16)v0.z; o.b[3] = (__bf16)v0.w;
    o.b[4] = (__bf16)v1.x; o.b[5] = (__bf16)v1.y; o.b[6] = (__bf16)v1.z; o.b[7] = (__bf16)v1.w;
    return o.i;
}

// Packed-W layout: [ct][kt32][s], s=0..511: wc=s>>8, j=(s>>6)&3, lane=s&63.
// Entry = int4 of W[pc][kt32*32+quad*8 .. +8], pc = ct*128+wc*64+j*16+(lane&15).
__device__ __forceinline__ void pk_decode(int rem, int KTbits, int& col, int& kk) {
    int ct = rem >> (KTbits + 9);
    int r2 = rem & ((1 << (KTbits + 9)) - 1);
    int kt = r2 >> 9, s = r2 & 511;
    int lane = s & 63;
    col = ct * 128 + ((s >> 8) << 6) + (((s >> 6) & 3) << 4) + (lane & 15);
    kk = kt * 32 + ((lane >> 4) & 3) * 8;
}

// ---------------- fused prep: pack weights, init, bins ----------------------
__global__ void prep_all(const float* __restrict__ Wmsg, const float* __restrict__ Wih,
                         const float* __restrict__ Whh, const float* __restrict__ fcW,
                         const float* __restrict__ x, const int* __restrict__ edges,
                         int4* __restrict__ WmPK, int4* __restrict__ WrznhPK,
                         int4* __restrict__ WfPK,
                         __hip_bfloat16* __restrict__ ab,
                         int* __restrict__ bcnt, int* __restrict__ bins) {
    int blk = blockIdx.x, tid = threadIdx.x;
    if (blk < 1024) {            // WmPK: per layer 16ct x 16kt x 512 = 131072
        int g = blk * 256 + tid;
        int l = g >> 17, rem = g & 131071;
        int col, kk; pk_decode(rem, 4, col, kk);
        WmPK[g] = cvt8(Wmsg + (size_t)l * 1048576 + (size_t)col * 512 + kk);
        return;
    }
    blk -= 1024;
    if (blk < 2048) {            // WrznhPK: per layer 16ct x 32kt x 512 = 262144
        // GATE-INTERLEAVED: packed col pc -> gate g=(pc>>4)&3,
        // hcol = (bcol*2 + wc)*16 + lm, bcol=pc>>7, wc=(pc>>6)&1, lm=pc&15.
        int g = blk * 256 + tid;
        int l = g >> 18, rem = g & 262143;
        int col, kk; pk_decode(rem, 5, col, kk);
        int gate = (col >> 4) & 3;
        int hcol = ((col >> 7) * 2 + ((col >> 6) & 1)) * 16 + (col & 15);
        int4 v = make_int4(0, 0, 0, 0);
        if (kk < 512) {
            // inc-half: W_ih rows {r:hcol, z:512+hcol, i_n:1024+hcol}; hn=0
            if (gate < 3) v = cvt8(Wih + (size_t)l * 786432 + (size_t)(gate * 512 + hcol) * 512 + kk);
        } else {
            // h-half: W_hh rows {r:hcol, z:512+hcol, hn:1024+hcol}; i_n=0
            if (gate < 2) v = cvt8(Whh + (size_t)l * 786432 + (size_t)(gate * 512 + hcol) * 512 + (kk - 512));
            else if (gate == 3) v = cvt8(Whh + (size_t)l * 786432 + (size_t)(1024 + hcol) * 512 + (kk - 512));
        }
        WrznhPK[g] = v;
        return;
    }
    blk -= 2048;
    if (blk < 128) {             // WfPK: 4ct x 16kt x 512 = 32768
        int g = blk * 256 + tid;
        int col, kk; pk_decode(g, 4, col, kk);
        WfPK[g] = cvt8(fcW + (size_t)col * 512 + kk);
        return;
    }
    blk -= 128;
    if (blk < 5000) {            // init: abA h-slot <- bf16(x)
        int i = blk * 1024 + tid * 4;
        float4 v = *(const float4*)(x + i);
        int m = i >> 9, c = i & 511;
        __hip_bfloat16 o[4] = {__float2bfloat16(v.x), __float2bfloat16(v.y),
                               __float2bfloat16(v.z), __float2bfloat16(v.w)};
        *(ulong1*)(ab + (size_t)m * 1024 + 512 + c) = *(ulong1*)o;
        return;
    }
    blk -= 5000;
    {                            // build_bins
        int i = blk * 256 + tid;
        if (i >= NT * NE) return;
        int src = edges[2 * i], tgt = edges[2 * i + 1];
        int t = i / NE;
        int b = tgt * NT + t;
        int pos = atomicAdd(&bcnt[b], 1);
        if (pos < CAP) bins[(size_t)b * CAP + pos] = src;
    }
}

// ---------------- gather: inc[n][c] = sum_t sum_src Msg[src][t*512+c] + cnt*bm
__global__ __launch_bounds__(256) void gather_msum(
    const int* __restrict__ bins, const int* __restrict__ bcnt,
    const float* __restrict__ bm, const __hip_bfloat16* __restrict__ Msg,
    __hip_bfloat16* __restrict__ inc) {
    int wave = threadIdx.x >> 6, lane = threadIdx.x & 63;
    int n = blockIdx.x * 4 + wave;
    int co = lane * 8;
    float acc[8] = {0, 0, 0, 0, 0, 0, 0, 0};
#pragma unroll
    for (int t = 0; t < NT; ++t) {
        int bi = n * NT + t;
        int cnt = bcnt[bi]; if (cnt > CAP) cnt = CAP;
        const int* bl = bins + (size_t)bi * CAP;
        for (int e = 0; e < cnt; ++e) {
            int src = bl[e];
            V16 v; v.i = *(const int4*)(Msg + (size_t)src * 2048 + t * 512 + co);
#pragma unroll
            for (int k = 0; k < 8; ++k) acc[k] += (float)v.b[k];
        }
        float4 b0 = *(const float4*)(bm + t * 512 + co);
        float4 b1 = *(const float4*)(bm + t * 512 + co + 4);
        float fc = (float)cnt;
        acc[0] += fc * b0.x; acc[1] += fc * b0.y; acc[2] += fc * b0.z; acc[3] += fc * b0.w;
        acc[4] += fc * b1.x; acc[5] += fc * b1.y; acc[6] += fc * b1.z; acc[7] += fc * b1.w;
    }
    V16 o;
#pragma unroll
    for (int k = 0; k < 8; ++k) o.b[k] = (__bf16)acc[k];
    *(int4*)(inc + (size_t)n * 1024 + co) = o.i;
}

// ---------------- monotone-uint float max encoding ----------------
__device__ __forceinline__ unsigned fenc(float f) {
    unsigned b = __float_as_uint(f);
    return b ^ (((int)b >> 31) | 0x80000000u);
}
__device__ __forceinline__ float fdec(unsigned u) {
    unsigned b = (u & 0x80000000u) ? (u ^ 0x80000000u) : ~u;
    return __uint_as_float(b);
}

// ---------------- GEMM: out = A(NNxK,lda) @ W^T, 128x128 tile, BK=64 ---------
// True depth-2 A pipeline (3 x 16KB LDS bufs), ping-pong B regs (no copy).
// Per iter: issue [B(kt+1) x8, A(kt+2) x4]; wait vmcnt(24)=through-A(kt);
// tails vmcnt(20)/vmcnt(8).
template<int MODE>
__global__ __launch_bounds__(256) void gemm(
    const __hip_bfloat16* __restrict__ A, int lda, int K,
    const int4* __restrict__ Wpk,
    const float* __restrict__ b0, const float* __restrict__ b1,
    __hip_bfloat16* __restrict__ obf, int ldo,
    unsigned* __restrict__ om) {
    __shared__ int4 sA4[3][1024];             // 48 KB: A staging; epilogue scratch
    __shared__ unsigned sm[128];
    __hip_bfloat16* lds = (__hip_bfloat16*)sA4;   // MODE 0 epilogue view
    float* ldsF = (float*)sA4;                    // MODE 1 epilogue view

    const int NB = (MODE == 3) ? 4 : 16;      // bcols in grid
    int bid = blockIdx.x;
    int xcd = bid & 7, kq = bid >> 3;
    int bcol = kq % NB;
    int brow = xcd + 8 * (kq / NB);           // 0..79 exactly covered
    int m0 = brow * 128, n0 = bcol * 128;

    int tid = threadIdx.x;
    int lane = tid & 63, wave = tid >> 6;
    int wr = wave >> 1, wc = wave & 1;
    int lm = lane & 15, quad = lane >> 4;
    int qx = (lm >> 1) & 3;                   // read-side bank swizzle

    const int KT32 = K >> 5;
    const int KT = K >> 6;       // BK64 tiles
    const int kend = KT;         // uniform (MODE 1 zero-structure handled per-j)
    const int4* Wp = Wpk + ((size_t)bcol * KT32 << 9) + wc * 256 + lane;

    // LDS per tile = two 32-k sub-slabs of 512 int4; bank-swizzled placement.
    auto issueA = [&](int kt, int p) {
        int k0 = kt << 6;
#pragma unroll
        for (int it = 0; it < 4; ++it) {
            int idx = it * 256 + tid;
            int s = idx >> 9, rem = idx & 511;
            int row = rem >> 2;
            int kc = (rem & 3) ^ ((row >> 1) & 3);    // src-side swizzle
            int gm = m0 + row; gm = gm < NN ? gm : NN - 1;
            gll16(A + (size_t)gm * lda + k0 + s * 32 + kc * 8,
                  (__hip_bfloat16*)(sA4[p]) + idx * 8);
        }
    };
    auto loadB = [&](int kt, int4 (&bb)[2][4]) {
#pragma unroll
        for (int s = 0; s < 2; ++s) {
            const int4* wn = Wp + ((size_t)(2 * kt + s) << 9);
#pragma unroll
            for (int j = 0; j < 4; ++j) bb[s][j] = wn[j * 64];
        }
    };

    f32x4 acc[4][4] = {};
    int4 bb0[2][4], bb1[2][4];
    issueA(0, 0);
    issueA(1, 1);
    loadB(0, bb0);

    auto ktbody = [&](int kt, int4 (&bbCur)[2][4], int4 (&bbNxt)[2][4]) {
        int p = kt % 3;
        if (kt + 1 < kend) loadB(kt + 1, bbNxt);          // B first (FIFO order)
        if (kt + 2 < kend) issueA(kt + 2, (kt + 2) % 3);  // then A
        __builtin_amdgcn_sched_barrier(0);
        if (kt + 2 < kend)      __builtin_amdgcn_s_waitcnt(0x4F78);  // vmcnt(24)
        else if (kt + 1 < kend) __builtin_amdgcn_s_waitcnt(0x4F74);  // vmcnt(20)
        else                    __builtin_amdgcn_s_waitcnt(0x0F78);  // vmcnt(8)
        __builtin_amdgcn_s_barrier();              // tile kt staged for all waves
        __builtin_amdgcn_sched_barrier(0);
        V16 a[4][2];
#pragma unroll
        for (int i = 0; i < 4; ++i)
#pragma unroll
            for (int s = 0; s < 2; ++s)
                a[i][s].i = sA4[p][s * 512 + (wr * 64 + i * 16 + lm) * 4 + (quad ^ qx)];
#pragma unroll
        for (int s = 0; s < 2; ++s)
#pragma unroll
            for (int i = 0; i < 4; ++i)
#pragma unroll
                for (int j = 0; j < 4; ++j) {
                    if (MODE == 1) {   // structural zeros: i_n no h-half, hn no inc-half
                        if (j == 2 && kt >= 8) continue;
                        if (j == 3 && kt < 8) continue;
                    }
                    V16 b; b.i = bbCur[s][j];
                    acc[i][j] = __builtin_amdgcn_mfma_f32_16x16x32_bf16(a[i][s].b, b.b, acc[i][j], 0, 0, 0);
                }
        __builtin_amdgcn_sched_barrier(0);
        __builtin_amdgcn_s_barrier();              // buf p reusable at iter kt+3
    };

    for (int k2 = 0; k2 < kend; k2 += 2) {       // kend always even (8 or 16)
        ktbody(k2, bb0, bb1);
        ktbody(k2 + 1, bb1, bb0);
    }

    if (MODE == 0) {
        // LDS-transpose epilogue, 2 row-phases of 64x128 bf16 (coalesced stores)
#pragma unroll
        for (int ph = 0; ph < 2; ++ph) {
            if (wr == ph) {
#pragma unroll
                for (int j = 0; j < 4; ++j) {
                    int c = wc * 64 + j * 16 + lm;
#pragma unroll
                    for (int i = 0; i < 4; ++i)
#pragma unroll
                        for (int r = 0; r < 4; ++r)
                            lds[(i * 16 + quad * 4 + r) * 128 + c] = __float2bfloat16(acc[i][j][r]);
                }
            }
            __syncthreads();
#pragma unroll
            for (int q = 0; q < 4; ++q) {
                int idx = q * 256 + tid;
                int rl = idx >> 4, c16 = idx & 15;
                int m = m0 + ph * 64 + rl;
                if (m < NN)
                    *(int4*)(obf + (size_t)m * ldo + n0 + c16 * 8) =
                        *(const int4*)(lds + rl * 128 + c16 * 8);
            }
            __syncthreads();
        }
    } else if (MODE == 1) {
        // fused GRU: acc[i][0..3] = r,z,i_n,hn partial sums for the SAME 16
        // h-cols (hcol = bcol*32 + wc*16 + lm). Gate math in fp32; blend's h
        // read as bf16 from the A operand's h-half (L2-hot; no h32 buffer).
        int c32 = wc * 16 + lm;
        int hcol = bcol * 32 + c32;
        float rb = b0[hcol] + b1[hcol];
        float zb = b0[512 + hcol] + b1[512 + hcol];
        float ib = b0[1024 + hcol];
        float hb = b1[1024 + hcol];
#pragma unroll
        for (int i = 0; i < 4; ++i)
#pragma unroll
            for (int r = 0; r < 4; ++r) {
                int rloc = wr * 64 + i * 16 + quad * 4 + r;
                int m = m0 + rloc;
                float hp = 0.f;
                if (m < NN) hp = bfl(*(const __bf16*)(A + (size_t)m * lda + 512 + hcol));
                float rr = 1.f / (1.f + __expf(-(acc[i][0][r] + rb)));
                float zz = 1.f / (1.f + __expf(-(acc[i][1][r] + zb)));
                float nx = (acc[i][2][r] + ib) + rr * (acc[i][3][r] + hb);
                float n = 1.f - 2.f / (__expf(2.f * nx) + 1.f);
                ldsF[rloc * 33 + c32] = (1.f - zz) * n + zz * hp;
            }
        __syncthreads();
        // coalesced writeout: 128 rows x 32 cols bf16 (next step's A h-slot)
#pragma unroll
        for (int q = 0; q < 4; ++q) {
            int idx = q * 256 + tid;              // 1024 4-col units
            int rl = idx >> 3, c4 = (idx & 7) * 4;
            int m = m0 + rl;
            if (m < NN) {
                const float* pf = ldsF + rl * 33 + c4;
                __hip_bfloat16 ob[4] = {__float2bfloat16(pf[0]), __float2bfloat16(pf[1]),
                                        __float2bfloat16(pf[2]), __float2bfloat16(pf[3])};
                *(ulong1*)(obf + (size_t)m * ldo + bcol * 32 + c4) = *(ulong1*)ob;
            }
        }
    } else {   // MODE 3: FC + column max
        if (tid < 128) sm[tid] = 0;
        __syncthreads();
#pragma unroll
        for (int j = 0; j < 4; ++j) {
            int c = wc * 64 + j * 16 + lm;
            float bias = b0[n0 + c];
            float mx = -INFINITY;
#pragma unroll
            for (int i = 0; i < 4; ++i) {
                int r0 = m0 + wr * 64 + i * 16 + quad * 4;
#pragma unroll
                for (int r = 0; r < 4; ++r) {
                    int m = r0 + r;
                    if (m < NN) mx = fmaxf(mx, acc[i][j][r] + bias);
                }
            }
            atomicMax(&sm[c], fenc(mx));
        }
        __syncthreads();
        if (tid < 128) atomicMax(&om[n0 + tid], sm[tid]);
    }
}

__global__ void writeout(const unsigned* __restrict__ om, float* __restrict__ o) {
    int c = threadIdx.x;
    o[c] = fdec(om[c]);
}

// ---------------- launch ----------------
extern "C" void kernel_launch(void* const* d_in, const int* in_sizes, int n_in,
                              void* d_out, int out_size, void* d_ws, size_t ws_size,
                              hipStream_t stream) {
    (void)in_sizes; (void)n_in; (void)out_size; (void)ws_size;
    const float* x    = (const float*)d_in[0];
    const int*   edges= (const int*)d_in[1];
    const float* Wmsg = (const float*)d_in[2];
    const float* bmsg = (const float*)d_in[3];
    const float* Wih  = (const float*)d_in[4];
    const float* Whh  = (const float*)d_in[5];
    const float* bih  = (const float*)d_in[6];
    const float* bhh  = (const float*)d_in[7];
    const float* fcW  = (const float*)d_in[8];
    const float* fcb  = (const float*)d_in[9];
    float* out = (float*)d_out;

    char* ws = (char*)d_ws;
    size_t off = 0;
    auto alloc = [&](size_t bytes) -> void* {
        void* p = ws + off; off += (bytes + 255) & ~(size_t)255; return p;
    };
    __hip_bfloat16* abA  = (__hip_bfloat16*)alloc((size_t)NN * 1024 * 2);   // 20.5 MB
    __hip_bfloat16* abB  = (__hip_bfloat16*)alloc((size_t)NN * 1024 * 2);   // 20.5 MB
    int*            bcnt = (int*)alloc((size_t)NN * NT * 4);                // 160 KB
    int*            bins = (int*)alloc((size_t)NN * NT * CAP * 4);          // 3.8 MB
    unsigned*       om   = (unsigned*)alloc(HD * 4);
    int4*           WmPK   = (int4*)alloc((size_t)2 * 131072 * 16);         // 4.2 MB
    int4*           WrznhPK= (int4*)alloc((size_t)2 * 262144 * 16);         // 8.4 MB
    int4*           WfPK   = (int4*)alloc((size_t)32768 * 16);              // 0.5 MB
    __hip_bfloat16* Msg  = (__hip_bfloat16*)alloc((size_t)NN * 2048 * 2);   // 41 MB
    // total ~99 MB

    hipMemsetAsync(bcnt, 0, (size_t)NN * NT * 4, stream);
    hipMemsetAsync(om, 0, HD * 4, stream);
    prep_all<<<1024 + 2048 + 128 + 5000 + 625, 256, 0, stream>>>(
        Wmsg, Wih, Whh, fcW, x, edges, WmPK, WrznhPK, WfPK, abA, bcnt, bins);

    for (int s = 0; s < 4; ++s) {
        int layer = s >> 1;
        __hip_bfloat16* cur = (s & 1) ? abB : abA;
        __hip_bfloat16* nxt = (s & 1) ? abA : abB;
        const int4* Wm = WmPK + (size_t)layer * 131072;
        const int4* Wz = WrznhPK + (size_t)layer * 262144;
        const float* bm = bmsg + (size_t)layer * 2048;
        const float* bi = bih + (size_t)layer * 1536;
        const float* bh = bhh + (size_t)layer * 1536;

        // Msg = h @ Wm^T  (out 2048, K=512)
        gemm<0><<<16 * GYROWS, 256, 0, stream>>>(cur + 512, 1024, 512, Wm,
            nullptr, nullptr, Msg, 2048, nullptr);
        // inc = gather(Msg) + cnt*bm -> cur[0:512]
        gather_msum<<<NN / 4, 256, 0, stream>>>(bins, bcnt, bm, Msg, cur);
        // fused GRU GEMM -> nxt h-slot (bf16)
        gemm<1><<<16 * GYROWS, 256, 0, stream>>>(cur, 1024, 1024, Wz,
            bi, bh, nxt + 512, 1024, nullptr);
    }
    // FC + column max (final h in abA h-slot after 4 steps)
    gemm<3><<<4 * GYROWS, 256, 0, stream>>>(abA + 512, 1024, 512, WfPK,
        fcb, nullptr, nullptr, 0, om);
    writeout<<<1, 512, 0, stream>>>(om, out);
}

// Round 6
// 601.123 us; speedup vs baseline: 1.4491x; 1.0165x over previous
//
#include <hip/hip_runtime.h>
#include <hip/hip_bf16.h>

// GGNN encoder: N=10000, H=512, T=4, E=40000, L=2 x 2 timesteps.
// fp32 inputs, fp32 output, bf16 MFMA internally.
//
// Per step (2 GEMM dispatches):
//   Msg  = h @ Wmsg_cat^T              (N x 2048, K=512)   [MODE 0]
//   inc  = gather-sum(Msg) + cnt*b     (N x 512)           [gather_msum]
//   h'   = fused GRU GEMM: [inc|h] @ Wrznh^T with GATE-INTERLEAVED packing
//          + split epilogue: (a,z)=((1-z)*n, z) via LDS, blend with
//          COALESCED h reads in the writeout phase -> h (bf16)  [MODE 1]
// Final: FC + column-max fused [MODE 3] -> writeout.
//
// r17 change (single lever, A/B vs r16's epilogue): r16's GRU epilogue read
//   h as 16 scalar scattered 2-byte loads/thread (5.2M per dispatch) and
//   regressed gemm1 74->86 us DESPITE 33% fewer bytes (falsifying the pure
//   BW-bound theory; the main loop has a ~74 us lockstep floor). Now the
//   epilogue stores (a,z) pairs to LDS (float2, stride 34 -> 2-way bank
//   aliasing = free) and the coalesced writeout phase computes a + z*h with
//   h loaded 8B/thread from the A operand's h-half (L2-hot). Identical
//   rounding to r16.
//
// Carried: fused GRU epilogue (gate-interleaved WrznhPK, per-kt j-skip),
// no-h32 (bf16 h only, -41 MB/step), XCD-aware swizzle, involutive LDS bank
// swizzle on A staging, BK=64, 3 rotating 16KB LDS bufs, true depth-2
// pipeline (ping-pong B regs, vmcnt(24/20/8) ladder).

#define NN 10000
#define HD 512
#define NT 4
#define NE 40000
#define CAP 24          // max edges per (target,type); P(Poisson(4)>24)~1e-14/bin
#define GYROWS 80       // padded to multiple of 8 for XCD swizzle (79 used)

typedef __bf16 bf16x8 __attribute__((ext_vector_type(8)));
typedef float f32x4 __attribute__((ext_vector_type(4)));
union V16 { int4 i; bf16x8 b; };

typedef __attribute__((address_space(1))) const unsigned int gu32;
typedef __attribute__((address_space(3))) unsigned int lu32;
__device__ __forceinline__ void gll16(const void* g, void* l) {
    __builtin_amdgcn_global_load_lds((gu32*)g, (lu32*)l, 16, 0, 0);
}

__device__ __forceinline__ float bfl(__bf16 v) { return (float)v; }

// pack 8 fp32 -> int4 of 8 bf16
__device__ __forceinline__ int4 cvt8(const float* __restrict__ s) {
    float4 v0 = *(const float4*)s, v1 = *(const float4*)(s + 4);
    V16 o;
    o.b[0] = (__bf16)v0.x; o.b[1] = (__bf16)v0.y; o.b[2] = (__bf16)v0.z; o.b[3] = (__bf16)v0.w;
    o.b[4] = (__bf16)v1.x; o.b[5] = (__bf16)v1.y; o.b[6] = (__bf16)v1.z; o.b[7] = (__bf16)v1.w;
    return o.i;
}

// Packed-W layout: [ct][kt32][s], s=0..511: wc=s>>8, j=(s>>6)&3, lane=s&63.
// Entry = int4 of W[pc][kt32*32+quad*8 .. +8], pc = ct*128+wc*64+j*16+(lane&15).
__device__ __forceinline__ void pk_decode(int rem, int KTbits, int& col, int& kk) {
    int ct = rem >> (KTbits + 9);
    int r2 = rem & ((1 << (KTbits + 9)) - 1);
    int kt = r2 >> 9, s = r2 & 511;
    int lane = s & 63;
    col = ct * 128 + ((s >> 8) << 6) + (((s >> 6) & 3) << 4) + (lane & 15);
    kk = kt * 32 + ((lane >> 4) & 3) * 8;
}

// ---------------- fused prep: pack weights, init, bins ----------------------
__global__ void prep_all(const float* __restrict__ Wmsg, const float* __restrict__ Wih,
                         const float* __restrict__ Whh, const float* __restrict__ fcW,
                         const float* __restrict__ x, const int* __restrict__ edges,
                         int4* __restrict__ WmPK, int4* __restrict__ WrznhPK,
                         int4* __restrict__ WfPK,
                         __hip_bfloat16* __restrict__ ab,
                         int* __restrict__ bcnt, int* __restrict__ bins) {
    int blk = blockIdx.x, tid = threadIdx.x;
    if (blk < 1024) {            // WmPK: per layer 16ct x 16kt x 512 = 131072
        int g = blk * 256 + tid;
        int l = g >> 17, rem = g & 131071;
        int col, kk; pk_decode(rem, 4, col, kk);
        WmPK[g] = cvt8(Wmsg + (size_t)l * 1048576 + (size_t)col * 512 + kk);
        return;
    }
    blk -= 1024;
    if (blk < 2048) {            // WrznhPK: per layer 16ct x 32kt x 512 = 262144
        // GATE-INTERLEAVED: packed col pc -> gate g=(pc>>4)&3,
        // hcol = (bcol*2 + wc)*16 + lm, bcol=pc>>7, wc=(pc>>6)&1, lm=pc&15.
        int g = blk * 256 + tid;
        int l = g >> 18, rem = g & 262143;
        int col, kk; pk_decode(rem, 5, col, kk);
        int gate = (col >> 4) & 3;
        int hcol = ((col >> 7) * 2 + ((col >> 6) & 1)) * 16 + (col & 15);
        int4 v = make_int4(0, 0, 0, 0);
        if (kk < 512) {
            // inc-half: W_ih rows {r:hcol, z:512+hcol, i_n:1024+hcol}; hn=0
            if (gate < 3) v = cvt8(Wih + (size_t)l * 786432 + (size_t)(gate * 512 + hcol) * 512 + kk);
        } else {
            // h-half: W_hh rows {r:hcol, z:512+hcol, hn:1024+hcol}; i_n=0
            if (gate < 2) v = cvt8(Whh + (size_t)l * 786432 + (size_t)(gate * 512 + hcol) * 512 + (kk - 512));
            else if (gate == 3) v = cvt8(Whh + (size_t)l * 786432 + (size_t)(1024 + hcol) * 512 + (kk - 512));
        }
        WrznhPK[g] = v;
        return;
    }
    blk -= 2048;
    if (blk < 128) {             // WfPK: 4ct x 16kt x 512 = 32768
        int g = blk * 256 + tid;
        int col, kk; pk_decode(g, 4, col, kk);
        WfPK[g] = cvt8(fcW + (size_t)col * 512 + kk);
        return;
    }
    blk -= 128;
    if (blk < 5000) {            // init: abA h-slot <- bf16(x)
        int i = blk * 1024 + tid * 4;
        float4 v = *(const float4*)(x + i);
        int m = i >> 9, c = i & 511;
        __hip_bfloat16 o[4] = {__float2bfloat16(v.x), __float2bfloat16(v.y),
                               __float2bfloat16(v.z), __float2bfloat16(v.w)};
        *(ulong1*)(ab + (size_t)m * 1024 + 512 + c) = *(ulong1*)o;
        return;
    }
    blk -= 5000;
    {                            // build_bins
        int i = blk * 256 + tid;
        if (i >= NT * NE) return;
        int src = edges[2 * i], tgt = edges[2 * i + 1];
        int t = i / NE;
        int b = tgt * NT + t;
        int pos = atomicAdd(&bcnt[b], 1);
        if (pos < CAP) bins[(size_t)b * CAP + pos] = src;
    }
}

// ---------------- gather: inc[n][c] = sum_t sum_src Msg[src][t*512+c] + cnt*bm
__global__ __launch_bounds__(256) void gather_msum(
    const int* __restrict__ bins, const int* __restrict__ bcnt,
    const float* __restrict__ bm, const __hip_bfloat16* __restrict__ Msg,
    __hip_bfloat16* __restrict__ inc) {
    int wave = threadIdx.x >> 6, lane = threadIdx.x & 63;
    int n = blockIdx.x * 4 + wave;
    int co = lane * 8;
    float acc[8] = {0, 0, 0, 0, 0, 0, 0, 0};
#pragma unroll
    for (int t = 0; t < NT; ++t) {
        int bi = n * NT + t;
        int cnt = bcnt[bi]; if (cnt > CAP) cnt = CAP;
        const int* bl = bins + (size_t)bi * CAP;
        for (int e = 0; e < cnt; ++e) {
            int src = bl[e];
            V16 v; v.i = *(const int4*)(Msg + (size_t)src * 2048 + t * 512 + co);
#pragma unroll
            for (int k = 0; k < 8; ++k) acc[k] += (float)v.b[k];
        }
        float4 b0 = *(const float4*)(bm + t * 512 + co);
        float4 b1 = *(const float4*)(bm + t * 512 + co + 4);
        float fc = (float)cnt;
        acc[0] += fc * b0.x; acc[1] += fc * b0.y; acc[2] += fc * b0.z; acc[3] += fc * b0.w;
        acc[4] += fc * b1.x; acc[5] += fc * b1.y; acc[6] += fc * b1.z; acc[7] += fc * b1.w;
    }
    V16 o;
#pragma unroll
    for (int k = 0; k < 8; ++k) o.b[k] = (__bf16)acc[k];
    *(int4*)(inc + (size_t)n * 1024 + co) = o.i;
}

// ---------------- monotone-uint float max encoding ----------------
__device__ __forceinline__ unsigned fenc(float f) {
    unsigned b = __float_as_uint(f);
    return b ^ (((int)b >> 31) | 0x80000000u);
}
__device__ __forceinline__ float fdec(unsigned u) {
    unsigned b = (u & 0x80000000u) ? (u ^ 0x80000000u) : ~u;
    return __uint_as_float(b);
}

// ---------------- GEMM: out = A(NNxK,lda) @ W^T, 128x128 tile, BK=64 ---------
// True depth-2 A pipeline (3 x 16KB LDS bufs), ping-pong B regs (no copy).
// Per iter: issue [B(kt+1) x8, A(kt+2) x4]; wait vmcnt(24)=through-A(kt);
// tails vmcnt(20)/vmcnt(8).
template<int MODE>
__global__ __launch_bounds__(256) void gemm(
    const __hip_bfloat16* __restrict__ A, int lda, int K,
    const int4* __restrict__ Wpk,
    const float* __restrict__ b0, const float* __restrict__ b1,
    __hip_bfloat16* __restrict__ obf, int ldo,
    unsigned* __restrict__ om) {
    __shared__ int4 sA4[3][1024];             // 48 KB: A staging; epilogue scratch
    __shared__ unsigned sm[128];
    __hip_bfloat16* lds = (__hip_bfloat16*)sA4;   // MODE 0 epilogue view
    float2* ldsZ = (float2*)sA4;                  // MODE 1 epilogue view (a,z)

    const int NB = (MODE == 3) ? 4 : 16;      // bcols in grid
    int bid = blockIdx.x;
    int xcd = bid & 7, kq = bid >> 3;
    int bcol = kq % NB;
    int brow = xcd + 8 * (kq / NB);           // 0..79 exactly covered
    int m0 = brow * 128, n0 = bcol * 128;

    int tid = threadIdx.x;
    int lane = tid & 63, wave = tid >> 6;
    int wr = wave >> 1, wc = wave & 1;
    int lm = lane & 15, quad = lane >> 4;
    int qx = (lm >> 1) & 3;                   // read-side bank swizzle

    const int KT32 = K >> 5;
    const int KT = K >> 6;       // BK64 tiles
    const int kend = KT;         // uniform (MODE 1 zero-structure handled per-j)
    const int4* Wp = Wpk + ((size_t)bcol * KT32 << 9) + wc * 256 + lane;

    // LDS per tile = two 32-k sub-slabs of 512 int4; bank-swizzled placement.
    auto issueA = [&](int kt, int p) {
        int k0 = kt << 6;
#pragma unroll
        for (int it = 0; it < 4; ++it) {
            int idx = it * 256 + tid;
            int s = idx >> 9, rem = idx & 511;
            int row = rem >> 2;
            int kc = (rem & 3) ^ ((row >> 1) & 3);    // src-side swizzle
            int gm = m0 + row; gm = gm < NN ? gm : NN - 1;
            gll16(A + (size_t)gm * lda + k0 + s * 32 + kc * 8,
                  (__hip_bfloat16*)(sA4[p]) + idx * 8);
        }
    };
    auto loadB = [&](int kt, int4 (&bb)[2][4]) {
#pragma unroll
        for (int s = 0; s < 2; ++s) {
            const int4* wn = Wp + ((size_t)(2 * kt + s) << 9);
#pragma unroll
            for (int j = 0; j < 4; ++j) bb[s][j] = wn[j * 64];
        }
    };

    f32x4 acc[4][4] = {};
    int4 bb0[2][4], bb1[2][4];
    issueA(0, 0);
    issueA(1, 1);
    loadB(0, bb0);

    auto ktbody = [&](int kt, int4 (&bbCur)[2][4], int4 (&bbNxt)[2][4]) {
        int p = kt % 3;
        if (kt + 1 < kend) loadB(kt + 1, bbNxt);          // B first (FIFO order)
        if (kt + 2 < kend) issueA(kt + 2, (kt + 2) % 3);  // then A
        __builtin_amdgcn_sched_barrier(0);
        if (kt + 2 < kend)      __builtin_amdgcn_s_waitcnt(0x4F78);  // vmcnt(24)
        else if (kt + 1 < kend) __builtin_amdgcn_s_waitcnt(0x4F74);  // vmcnt(20)
        else                    __builtin_amdgcn_s_waitcnt(0x0F78);  // vmcnt(8)
        __builtin_amdgcn_s_barrier();              // tile kt staged for all waves
        __builtin_amdgcn_sched_barrier(0);
        V16 a[4][2];
#pragma unroll
        for (int i = 0; i < 4; ++i)
#pragma unroll
            for (int s = 0; s < 2; ++s)
                a[i][s].i = sA4[p][s * 512 + (wr * 64 + i * 16 + lm) * 4 + (quad ^ qx)];
#pragma unroll
        for (int s = 0; s < 2; ++s)
#pragma unroll
            for (int i = 0; i < 4; ++i)
#pragma unroll
                for (int j = 0; j < 4; ++j) {
                    if (MODE == 1) {   // structural zeros: i_n no h-half, hn no inc-half
                        if (j == 2 && kt >= 8) continue;
                        if (j == 3 && kt < 8) continue;
                    }
                    V16 b; b.i = bbCur[s][j];
                    acc[i][j] = __builtin_amdgcn_mfma_f32_16x16x32_bf16(a[i][s].b, b.b, acc[i][j], 0, 0, 0);
                }
        __builtin_amdgcn_sched_barrier(0);
        __builtin_amdgcn_s_barrier();              // buf p reusable at iter kt+3
    };

    for (int k2 = 0; k2 < kend; k2 += 2) {       // kend always even (8 or 16)
        ktbody(k2, bb0, bb1);
        ktbody(k2 + 1, bb1, bb0);
    }

    if (MODE == 0) {
        // LDS-transpose epilogue, 2 row-phases of 64x128 bf16 (coalesced stores)
#pragma unroll
        for (int ph = 0; ph < 2; ++ph) {
            if (wr == ph) {
#pragma unroll
                for (int j = 0; j < 4; ++j) {
                    int c = wc * 64 + j * 16 + lm;
#pragma unroll
                    for (int i = 0; i < 4; ++i)
#pragma unroll
                        for (int r = 0; r < 4; ++r)
                            lds[(i * 16 + quad * 4 + r) * 128 + c] = __float2bfloat16(acc[i][j][r]);
                }
            }
            __syncthreads();
#pragma unroll
            for (int q = 0; q < 4; ++q) {
                int idx = q * 256 + tid;
                int rl = idx >> 4, c16 = idx & 15;
                int m = m0 + ph * 64 + rl;
                if (m < NN)
                    *(int4*)(obf + (size_t)m * ldo + n0 + c16 * 8) =
                        *(const int4*)(lds + rl * 128 + c16 * 8);
            }
            __syncthreads();
        }
    } else if (MODE == 1) {
        // fused GRU, split blend: epilogue computes a=(1-z)*n and z (fp32),
        // stores (a,z) pairs to LDS; writeout phase blends with COALESCED
        // bf16 h loads from the A operand's h-half. Same rounding as r16.
        int c32 = wc * 16 + lm;
        int hcol = bcol * 32 + c32;
        float rb = b0[hcol] + b1[hcol];
        float zb = b0[512 + hcol] + b1[512 + hcol];
        float ib = b0[1024 + hcol];
        float hb = b1[1024 + hcol];
#pragma unroll
        for (int i = 0; i < 4; ++i)
#pragma unroll
            for (int r = 0; r < 4; ++r) {
                int rloc = wr * 64 + i * 16 + quad * 4 + r;
                float rr = 1.f / (1.f + __expf(-(acc[i][0][r] + rb)));
                float zz = 1.f / (1.f + __expf(-(acc[i][1][r] + zb)));
                float nx = (acc[i][2][r] + ib) + rr * (acc[i][3][r] + hb);
                float n = 1.f - 2.f / (__expf(2.f * nx) + 1.f);
                ldsZ[rloc * 34 + c32] = make_float2((1.f - zz) * n, zz);
            }
        __syncthreads();
        // coalesced writeout: 128 rows x 32 cols bf16 (next step's A h-slot);
        // h read 8B/thread from A[m][512+bcol*32+c4..] (64B per 8 threads).
#pragma unroll
        for (int q = 0; q < 4; ++q) {
            int idx = q * 256 + tid;              // 1024 4-col units
            int rl = idx >> 3, c4 = (idx & 7) * 4;
            int m = m0 + rl;
            if (m < NN) {
                ulong1 hraw = *(const ulong1*)(A + (size_t)m * lda + 512 + bcol * 32 + c4);
                const __bf16* hb4 = (const __bf16*)&hraw;
                const float2* pz = ldsZ + rl * 34 + c4;
                __hip_bfloat16 ob[4];
#pragma unroll
                for (int e = 0; e < 4; ++e) {
                    float2 az = pz[e];
                    ob[e] = __float2bfloat16(az.x + az.y * bfl(hb4[e]));
                }
                *(ulong1*)(obf + (size_t)m * ldo + bcol * 32 + c4) = *(ulong1*)ob;
            }
        }
    } else {   // MODE 3: FC + column max
        if (tid < 128) sm[tid] = 0;
        __syncthreads();
#pragma unroll
        for (int j = 0; j < 4; ++j) {
            int c = wc * 64 + j * 16 + lm;
            float bias = b0[n0 + c];
            float mx = -INFINITY;
#pragma unroll
            for (int i = 0; i < 4; ++i) {
                int r0 = m0 + wr * 64 + i * 16 + quad * 4;
#pragma unroll
                for (int r = 0; r < 4; ++r) {
                    int m = r0 + r;
                    if (m < NN) mx = fmaxf(mx, acc[i][j][r] + bias);
                }
            }
            atomicMax(&sm[c], fenc(mx));
        }
        __syncthreads();
        if (tid < 128) atomicMax(&om[n0 + tid], sm[tid]);
    }
}

__global__ void writeout(const unsigned* __restrict__ om, float* __restrict__ o) {
    int c = threadIdx.x;
    o[c] = fdec(om[c]);
}

// ---------------- launch ----------------
extern "C" void kernel_launch(void* const* d_in, const int* in_sizes, int n_in,
                              void* d_out, int out_size, void* d_ws, size_t ws_size,
                              hipStream_t stream) {
    (void)in_sizes; (void)n_in; (void)out_size; (void)ws_size;
    const float* x    = (const float*)d_in[0];
    const int*   edges= (const int*)d_in[1];
    const float* Wmsg = (const float*)d_in[2];
    const float* bmsg = (const float*)d_in[3];
    const float* Wih  = (const float*)d_in[4];
    const float* Whh  = (const float*)d_in[5];
    const float* bih  = (const float*)d_in[6];
    const float* bhh  = (const float*)d_in[7];
    const float* fcW  = (const float*)d_in[8];
    const float* fcb  = (const float*)d_in[9];
    float* out = (float*)d_out;

    char* ws = (char*)d_ws;
    size_t off = 0;
    auto alloc = [&](size_t bytes) -> void* {
        void* p = ws + off; off += (bytes + 255) & ~(size_t)255; return p;
    };
    __hip_bfloat16* abA  = (__hip_bfloat16*)alloc((size_t)NN * 1024 * 2);   // 20.5 MB
    __hip_bfloat16* abB  = (__hip_bfloat16*)alloc((size_t)NN * 1024 * 2);   // 20.5 MB
    int*            bcnt = (int*)alloc((size_t)NN * NT * 4);                // 160 KB
    int*            bins = (int*)alloc((size_t)NN * NT * CAP * 4);          // 3.8 MB
    unsigned*       om   = (unsigned*)alloc(HD * 4);
    int4*           WmPK   = (int4*)alloc((size_t)2 * 131072 * 16);         // 4.2 MB
    int4*           WrznhPK= (int4*)alloc((size_t)2 * 262144 * 16);         // 8.4 MB
    int4*           WfPK   = (int4*)alloc((size_t)32768 * 16);              // 0.5 MB
    __hip_bfloat16* Msg  = (__hip_bfloat16*)alloc((size_t)NN * 2048 * 2);   // 41 MB
    // total ~99 MB

    hipMemsetAsync(bcnt, 0, (size_t)NN * NT * 4, stream);
    hipMemsetAsync(om, 0, HD * 4, stream);
    prep_all<<<1024 + 2048 + 128 + 5000 + 625, 256, 0, stream>>>(
        Wmsg, Wih, Whh, fcW, x, edges, WmPK, WrznhPK, WfPK, abA, bcnt, bins);

    for (int s = 0; s < 4; ++s) {
        int layer = s >> 1;
        __hip_bfloat16* cur = (s & 1) ? abB : abA;
        __hip_bfloat16* nxt = (s & 1) ? abA : abB;
        const int4* Wm = WmPK + (size_t)layer * 131072;
        const int4* Wz = WrznhPK + (size_t)layer * 262144;
        const float* bm = bmsg + (size_t)layer * 2048;
        const float* bi = bih + (size_t)layer * 1536;
        const float* bh = bhh + (size_t)layer * 1536;

        // Msg = h @ Wm^T  (out 2048, K=512)
        gemm<0><<<16 * GYROWS, 256, 0, stream>>>(cur + 512, 1024, 512, Wm,
            nullptr, nullptr, Msg, 2048, nullptr);
        // inc = gather(Msg) + cnt*bm -> cur[0:512]
        gather_msum<<<NN / 4, 256, 0, stream>>>(bins, bcnt, bm, Msg, cur);
        // fused GRU GEMM -> nxt h-slot (bf16)
        gemm<1><<<16 * GYROWS, 256, 0, stream>>>(cur, 1024, 1024, Wz,
            bi, bh, nxt + 512, 1024, nullptr);
    }
    // FC + column max (final h in abA h-slot after 4 steps)
    gemm<3><<<4 * GYROWS, 256, 0, stream>>>(abA + 512, 1024, 512, WfPK,
        fcb, nullptr, nullptr, 0, om);
    writeout<<<1, 512, 0, stream>>>(om, out);
}

// Round 7
// 574.124 us; speedup vs baseline: 1.5173x; 1.0470x over previous
//
#include <hip/hip_runtime.h>
#include <hip/hip_bf16.h>

// GGNN encoder: N=10000, H=512, T=4, E=40000, L=2 x 2 timesteps.
// fp32 inputs, fp32 output, bf16 MFMA internally.
//
// Per step (2 GEMM dispatches):
//   Msg  = h @ Wmsg_cat^T              (N x 2048, K=512)   [MODE 0]
//   inc  = gather-sum(Msg) + cnt*b     (N x 512)           [gather_msum]
//   h'   = fused GRU GEMM: [inc|h] @ Wrznh^T with GATE-INTERLEAVED packing
//          + split epilogue: (a,z)=((1-z)*n, z) via LDS, blend with
//          COALESCED h reads in the writeout phase -> h (bf16)  [MODE 1]
// Final: FC + column-max fused [MODE 3] -> writeout.
//
// r18 change (single lever): ONE barrier per K-iter (was 2).
//   All pipes still idle (Mfma 20/VALU 25/HBM 13) with ~1.4-2 blocks
//   resident -> lockstep barrier cost dominates. The buf-reuse barrier is
//   deleted by MOVING issueA(kt+2) to AFTER the staging barrier: a wave
//   reaches barrier(kt) only after its MFMA(kt-1) consumed its ds_reads
//   (compiler lgkmcnt), so barrier(kt) certifies ALL waves' reads of
//   buf (kt-1)%3==(kt+2)%3 are complete -> post-barrier overwrite is
//   race-free by ordering, not timing. sched_barrier(0) after s_barrier
//   pins the gll16 below the barrier. New ladder: vmcnt(20) steady
//   (entering {A(kt),B(kt),A(kt+1)}=16, +8 B -> 24, retire A(kt)),
//   vmcnt(8) last iter.
//
// Carried: fused GRU epilogue (gate-interleaved WrznhPK, per-kt j-skip),
// split (a,z)-LDS blend with coalesced h reads (r17), no-h32 (r16),
// XCD-aware swizzle, involutive LDS bank swizzle on A staging, BK=64,
// 3 rotating 16KB LDS bufs, depth-2 ping-pong B regs.

#define NN 10000
#define HD 512
#define NT 4
#define NE 40000
#define CAP 24          // max edges per (target,type); P(Poisson(4)>24)~1e-14/bin
#define GYROWS 80       // padded to multiple of 8 for XCD swizzle (79 used)

typedef __bf16 bf16x8 __attribute__((ext_vector_type(8)));
typedef float f32x4 __attribute__((ext_vector_type(4)));
union V16 { int4 i; bf16x8 b; };

typedef __attribute__((address_space(1))) const unsigned int gu32;
typedef __attribute__((address_space(3))) unsigned int lu32;
__device__ __forceinline__ void gll16(const void* g, void* l) {
    __builtin_amdgcn_global_load_lds((gu32*)g, (lu32*)l, 16, 0, 0);
}

__device__ __forceinline__ float bfl(__bf16 v) { return (float)v; }

// pack 8 fp32 -> int4 of 8 bf16
__device__ __forceinline__ int4 cvt8(const float* __restrict__ s) {
    float4 v0 = *(const float4*)s, v1 = *(const float4*)(s + 4);
    V16 o;
    o.b[0] = (__bf16)v0.x; o.b[1] = (__bf16)v0.y; o.b[2] = (__bf16)v0.z; o.b[3] = (__bf16)v0.w;
    o.b[4] = (__bf16)v1.x; o.b[5] = (__bf16)v1.y; o.b[6] = (__bf16)v1.z; o.b[7] = (__bf16)v1.w;
    return o.i;
}

// Packed-W layout: [ct][kt32][s], s=0..511: wc=s>>8, j=(s>>6)&3, lane=s&63.
// Entry = int4 of W[pc][kt32*32+quad*8 .. +8], pc = ct*128+wc*64+j*16+(lane&15).
__device__ __forceinline__ void pk_decode(int rem, int KTbits, int& col, int& kk) {
    int ct = rem >> (KTbits + 9);
    int r2 = rem & ((1 << (KTbits + 9)) - 1);
    int kt = r2 >> 9, s = r2 & 511;
    int lane = s & 63;
    col = ct * 128 + ((s >> 8) << 6) + (((s >> 6) & 3) << 4) + (lane & 15);
    kk = kt * 32 + ((lane >> 4) & 3) * 8;
}

// ---------------- fused prep: pack weights, init, bins ----------------------
__global__ void prep_all(const float* __restrict__ Wmsg, const float* __restrict__ Wih,
                         const float* __restrict__ Whh, const float* __restrict__ fcW,
                         const float* __restrict__ x, const int* __restrict__ edges,
                         int4* __restrict__ WmPK, int4* __restrict__ WrznhPK,
                         int4* __restrict__ WfPK,
                         __hip_bfloat16* __restrict__ ab,
                         int* __restrict__ bcnt, int* __restrict__ bins) {
    int blk = blockIdx.x, tid = threadIdx.x;
    if (blk < 1024) {            // WmPK: per layer 16ct x 16kt x 512 = 131072
        int g = blk * 256 + tid;
        int l = g >> 17, rem = g & 131071;
        int col, kk; pk_decode(rem, 4, col, kk);
        WmPK[g] = cvt8(Wmsg + (size_t)l * 1048576 + (size_t)col * 512 + kk);
        return;
    }
    blk -= 1024;
    if (blk < 2048) {            // WrznhPK: per layer 16ct x 32kt x 512 = 262144
        // GATE-INTERLEAVED: packed col pc -> gate g=(pc>>4)&3,
        // hcol = (bcol*2 + wc)*16 + lm, bcol=pc>>7, wc=(pc>>6)&1, lm=pc&15.
        int g = blk * 256 + tid;
        int l = g >> 18, rem = g & 262143;
        int col, kk; pk_decode(rem, 5, col, kk);
        int gate = (col >> 4) & 3;
        int hcol = ((col >> 7) * 2 + ((col >> 6) & 1)) * 16 + (col & 15);
        int4 v = make_int4(0, 0, 0, 0);
        if (kk < 512) {
            // inc-half: W_ih rows {r:hcol, z:512+hcol, i_n:1024+hcol}; hn=0
            if (gate < 3) v = cvt8(Wih + (size_t)l * 786432 + (size_t)(gate * 512 + hcol) * 512 + kk);
        } else {
            // h-half: W_hh rows {r:hcol, z:512+hcol, hn:1024+hcol}; i_n=0
            if (gate < 2) v = cvt8(Whh + (size_t)l * 786432 + (size_t)(gate * 512 + hcol) * 512 + (kk - 512));
            else if (gate == 3) v = cvt8(Whh + (size_t)l * 786432 + (size_t)(1024 + hcol) * 512 + (kk - 512));
        }
        WrznhPK[g] = v;
        return;
    }
    blk -= 2048;
    if (blk < 128) {             // WfPK: 4ct x 16kt x 512 = 32768
        int g = blk * 256 + tid;
        int col, kk; pk_decode(g, 4, col, kk);
        WfPK[g] = cvt8(fcW + (size_t)col * 512 + kk);
        return;
    }
    blk -= 128;
    if (blk < 5000) {            // init: abA h-slot <- bf16(x)
        int i = blk * 1024 + tid * 4;
        float4 v = *(const float4*)(x + i);
        int m = i >> 9, c = i & 511;
        __hip_bfloat16 o[4] = {__float2bfloat16(v.x), __float2bfloat16(v.y),
                               __float2bfloat16(v.z), __float2bfloat16(v.w)};
        *(ulong1*)(ab + (size_t)m * 1024 + 512 + c) = *(ulong1*)o;
        return;
    }
    blk -= 5000;
    {                            // build_bins
        int i = blk * 256 + tid;
        if (i >= NT * NE) return;
        int src = edges[2 * i], tgt = edges[2 * i + 1];
        int t = i / NE;
        int b = tgt * NT + t;
        int pos = atomicAdd(&bcnt[b], 1);
        if (pos < CAP) bins[(size_t)b * CAP + pos] = src;
    }
}

// ---------------- gather: inc[n][c] = sum_t sum_src Msg[src][t*512+c] + cnt*bm
__global__ __launch_bounds__(256) void gather_msum(
    const int* __restrict__ bins, const int* __restrict__ bcnt,
    const float* __restrict__ bm, const __hip_bfloat16* __restrict__ Msg,
    __hip_bfloat16* __restrict__ inc) {
    int wave = threadIdx.x >> 6, lane = threadIdx.x & 63;
    int n = blockIdx.x * 4 + wave;
    int co = lane * 8;
    float acc[8] = {0, 0, 0, 0, 0, 0, 0, 0};
#pragma unroll
    for (int t = 0; t < NT; ++t) {
        int bi = n * NT + t;
        int cnt = bcnt[bi]; if (cnt > CAP) cnt = CAP;
        const int* bl = bins + (size_t)bi * CAP;
        for (int e = 0; e < cnt; ++e) {
            int src = bl[e];
            V16 v; v.i = *(const int4*)(Msg + (size_t)src * 2048 + t * 512 + co);
#pragma unroll
            for (int k = 0; k < 8; ++k) acc[k] += (float)v.b[k];
        }
        float4 b0 = *(const float4*)(bm + t * 512 + co);
        float4 b1 = *(const float4*)(bm + t * 512 + co + 4);
        float fc = (float)cnt;
        acc[0] += fc * b0.x; acc[1] += fc * b0.y; acc[2] += fc * b0.z; acc[3] += fc * b0.w;
        acc[4] += fc * b1.x; acc[5] += fc * b1.y; acc[6] += fc * b1.z; acc[7] += fc * b1.w;
    }
    V16 o;
#pragma unroll
    for (int k = 0; k < 8; ++k) o.b[k] = (__bf16)acc[k];
    *(int4*)(inc + (size_t)n * 1024 + co) = o.i;
}

// ---------------- monotone-uint float max encoding ----------------
__device__ __forceinline__ unsigned fenc(float f) {
    unsigned b = __float_as_uint(f);
    return b ^ (((int)b >> 31) | 0x80000000u);
}
__device__ __forceinline__ float fdec(unsigned u) {
    unsigned b = (u & 0x80000000u) ? (u ^ 0x80000000u) : ~u;
    return __uint_as_float(b);
}

// ---------------- GEMM: out = A(NNxK,lda) @ W^T, 128x128 tile, BK=64 ---------
// ONE barrier per K-iter: [loadB(kt+1); vmcnt(20); s_barrier; ds_read(kt);
// issueA(kt+2) (post-barrier => overwrite of buf (kt-1)%3 is race-free);
// MFMA]. Depth-2 ping-pong B regs; 3 rotating 16KB LDS bufs.
template<int MODE>
__global__ __launch_bounds__(256) void gemm(
    const __hip_bfloat16* __restrict__ A, int lda, int K,
    const int4* __restrict__ Wpk,
    const float* __restrict__ b0, const float* __restrict__ b1,
    __hip_bfloat16* __restrict__ obf, int ldo,
    unsigned* __restrict__ om) {
    __shared__ int4 sA4[3][1024];             // 48 KB: A staging; epilogue scratch
    __shared__ unsigned sm[128];
    __hip_bfloat16* lds = (__hip_bfloat16*)sA4;   // MODE 0 epilogue view
    float2* ldsZ = (float2*)sA4;                  // MODE 1 epilogue view (a,z)

    const int NB = (MODE == 3) ? 4 : 16;      // bcols in grid
    int bid = blockIdx.x;
    int xcd = bid & 7, kq = bid >> 3;
    int bcol = kq % NB;
    int brow = xcd + 8 * (kq / NB);           // 0..79 exactly covered
    int m0 = brow * 128, n0 = bcol * 128;

    int tid = threadIdx.x;
    int lane = tid & 63, wave = tid >> 6;
    int wr = wave >> 1, wc = wave & 1;
    int lm = lane & 15, quad = lane >> 4;
    int qx = (lm >> 1) & 3;                   // read-side bank swizzle

    const int KT32 = K >> 5;
    const int KT = K >> 6;       // BK64 tiles
    const int kend = KT;         // uniform (MODE 1 zero-structure handled per-j)
    const int4* Wp = Wpk + ((size_t)bcol * KT32 << 9) + wc * 256 + lane;

    // LDS per tile = two 32-k sub-slabs of 512 int4; bank-swizzled placement.
    auto issueA = [&](int kt, int p) {
        int k0 = kt << 6;
#pragma unroll
        for (int it = 0; it < 4; ++it) {
            int idx = it * 256 + tid;
            int s = idx >> 9, rem = idx & 511;
            int row = rem >> 2;
            int kc = (rem & 3) ^ ((row >> 1) & 3);    // src-side swizzle
            int gm = m0 + row; gm = gm < NN ? gm : NN - 1;
            gll16(A + (size_t)gm * lda + k0 + s * 32 + kc * 8,
                  (__hip_bfloat16*)(sA4[p]) + idx * 8);
        }
    };
    auto loadB = [&](int kt, int4 (&bb)[2][4]) {
#pragma unroll
        for (int s = 0; s < 2; ++s) {
            const int4* wn = Wp + ((size_t)(2 * kt + s) << 9);
#pragma unroll
            for (int j = 0; j < 4; ++j) bb[s][j] = wn[j * 64];
        }
    };

    f32x4 acc[4][4] = {};
    int4 bb0[2][4], bb1[2][4];
    issueA(0, 0);
    issueA(1, 1);
    loadB(0, bb0);

    auto ktbody = [&](int kt, int4 (&bbCur)[2][4], int4 (&bbNxt)[2][4]) {
        int p = kt % 3;
        if (kt + 1 < kend) loadB(kt + 1, bbNxt);
        __builtin_amdgcn_sched_barrier(0);
        if (kt + 1 < kend) __builtin_amdgcn_s_waitcnt(0x4F74);  // vmcnt(20): A(kt) retired
        else               __builtin_amdgcn_s_waitcnt(0x0F78);  // vmcnt(8) last iter
        __builtin_amdgcn_s_barrier();   // tile kt staged; all reads of buf
                                        // (kt-1)%3 complete (consumed pre-barrier)
        __builtin_amdgcn_sched_barrier(0);   // pins issueA below the barrier
        V16 a[4][2];
#pragma unroll
        for (int i = 0; i < 4; ++i)
#pragma unroll
            for (int s = 0; s < 2; ++s)
                a[i][s].i = sA4[p][s * 512 + (wr * 64 + i * 16 + lm) * 4 + (quad ^ qx)];
        if (kt + 2 < kend) issueA(kt + 2, (kt + 2) % 3);  // overwrites (kt-1)%3: safe
#pragma unroll
        for (int s = 0; s < 2; ++s)
#pragma unroll
            for (int i = 0; i < 4; ++i)
#pragma unroll
                for (int j = 0; j < 4; ++j) {
                    if (MODE == 1) {   // structural zeros: i_n no h-half, hn no inc-half
                        if (j == 2 && kt >= 8) continue;
                        if (j == 3 && kt < 8) continue;
                    }
                    V16 b; b.i = bbCur[s][j];
                    acc[i][j] = __builtin_amdgcn_mfma_f32_16x16x32_bf16(a[i][s].b, b.b, acc[i][j], 0, 0, 0);
                }
        __builtin_amdgcn_sched_barrier(0);
    };

    for (int k2 = 0; k2 < kend; k2 += 2) {       // kend always even (8 or 16)
        ktbody(k2, bb0, bb1);
        ktbody(k2 + 1, bb1, bb0);
    }

    if (MODE == 0) {
        // LDS-transpose epilogue, 2 row-phases of 64x128 bf16 (coalesced stores)
        __syncthreads();   // acc final; sA4 reusable as scratch
#pragma unroll
        for (int ph = 0; ph < 2; ++ph) {
            if (wr == ph) {
#pragma unroll
                for (int j = 0; j < 4; ++j) {
                    int c = wc * 64 + j * 16 + lm;
#pragma unroll
                    for (int i = 0; i < 4; ++i)
#pragma unroll
                        for (int r = 0; r < 4; ++r)
                            lds[(i * 16 + quad * 4 + r) * 128 + c] = __float2bfloat16(acc[i][j][r]);
                }
            }
            __syncthreads();
#pragma unroll
            for (int q = 0; q < 4; ++q) {
                int idx = q * 256 + tid;
                int rl = idx >> 4, c16 = idx & 15;
                int m = m0 + ph * 64 + rl;
                if (m < NN)
                    *(int4*)(obf + (size_t)m * ldo + n0 + c16 * 8) =
                        *(const int4*)(lds + rl * 128 + c16 * 8);
            }
            __syncthreads();
        }
    } else if (MODE == 1) {
        // fused GRU, split blend: epilogue computes a=(1-z)*n and z (fp32),
        // stores (a,z) pairs to LDS; writeout phase blends with COALESCED
        // bf16 h loads from the A operand's h-half. Same rounding as r16.
        __syncthreads();   // acc final; sA4 reusable as scratch
        int c32 = wc * 16 + lm;
        int hcol = bcol * 32 + c32;
        float rb = b0[hcol] + b1[hcol];
        float zb = b0[512 + hcol] + b1[512 + hcol];
        float ib = b0[1024 + hcol];
        float hb = b1[1024 + hcol];
#pragma unroll
        for (int i = 0; i < 4; ++i)
#pragma unroll
            for (int r = 0; r < 4; ++r) {
                int rloc = wr * 64 + i * 16 + quad * 4 + r;
                float rr = 1.f / (1.f + __expf(-(acc[i][0][r] + rb)));
                float zz = 1.f / (1.f + __expf(-(acc[i][1][r] + zb)));
                float nx = (acc[i][2][r] + ib) + rr * (acc[i][3][r] + hb);
                float n = 1.f - 2.f / (__expf(2.f * nx) + 1.f);
                ldsZ[rloc * 34 + c32] = make_float2((1.f - zz) * n, zz);
            }
        __syncthreads();
        // coalesced writeout: 128 rows x 32 cols bf16 (next step's A h-slot);
        // h read 8B/thread from A[m][512+bcol*32+c4..] (64B per 8 threads).
#pragma unroll
        for (int q = 0; q < 4; ++q) {
            int idx = q * 256 + tid;              // 1024 4-col units
            int rl = idx >> 3, c4 = (idx & 7) * 4;
            int m = m0 + rl;
            if (m < NN) {
                ulong1 hraw = *(const ulong1*)(A + (size_t)m * lda + 512 + bcol * 32 + c4);
                const __bf16* hb4 = (const __bf16*)&hraw;
                const float2* pz = ldsZ + rl * 34 + c4;
                __hip_bfloat16 ob[4];
#pragma unroll
                for (int e = 0; e < 4; ++e) {
                    float2 az = pz[e];
                    ob[e] = __float2bfloat16(az.x + az.y * bfl(hb4[e]));
                }
                *(ulong1*)(obf + (size_t)m * ldo + bcol * 32 + c4) = *(ulong1*)ob;
            }
        }
    } else {   // MODE 3: FC + column max
        if (tid < 128) sm[tid] = 0;
        __syncthreads();
#pragma unroll
        for (int j = 0; j < 4; ++j) {
            int c = wc * 64 + j * 16 + lm;
            float bias = b0[n0 + c];
            float mx = -INFINITY;
#pragma unroll
            for (int i = 0; i < 4; ++i) {
                int r0 = m0 + wr * 64 + i * 16 + quad * 4;
#pragma unroll
                for (int r = 0; r < 4; ++r) {
                    int m = r0 + r;
                    if (m < NN) mx = fmaxf(mx, acc[i][j][r] + bias);
                }
            }
            atomicMax(&sm[c], fenc(mx));
        }
        __syncthreads();
        if (tid < 128) atomicMax(&om[n0 + tid], sm[tid]);
    }
}

__global__ void writeout(const unsigned* __restrict__ om, float* __restrict__ o) {
    int c = threadIdx.x;
    o[c] = fdec(om[c]);
}

// ---------------- launch ----------------
extern "C" void kernel_launch(void* const* d_in, const int* in_sizes, int n_in,
                              void* d_out, int out_size, void* d_ws, size_t ws_size,
                              hipStream_t stream) {
    (void)in_sizes; (void)n_in; (void)out_size; (void)ws_size;
    const float* x    = (const float*)d_in[0];
    const int*   edges= (const int*)d_in[1];
    const float* Wmsg = (const float*)d_in[2];
    const float* bmsg = (const float*)d_in[3];
    const float* Wih  = (const float*)d_in[4];
    const float* Whh  = (const float*)d_in[5];
    const float* bih  = (const float*)d_in[6];
    const float* bhh  = (const float*)d_in[7];
    const float* fcW  = (const float*)d_in[8];
    const float* fcb  = (const float*)d_in[9];
    float* out = (float*)d_out;

    char* ws = (char*)d_ws;
    size_t off = 0;
    auto alloc = [&](size_t bytes) -> void* {
        void* p = ws + off; off += (bytes + 255) & ~(size_t)255; return p;
    };
    __hip_bfloat16* abA  = (__hip_bfloat16*)alloc((size_t)NN * 1024 * 2);   // 20.5 MB
    __hip_bfloat16* abB  = (__hip_bfloat16*)alloc((size_t)NN * 1024 * 2);   // 20.5 MB
    int*            bcnt = (int*)alloc((size_t)NN * NT * 4);                // 160 KB
    int*            bins = (int*)alloc((size_t)NN * NT * CAP * 4);          // 3.8 MB
    unsigned*       om   = (unsigned*)alloc(HD * 4);
    int4*           WmPK   = (int4*)alloc((size_t)2 * 131072 * 16);         // 4.2 MB
    int4*           WrznhPK= (int4*)alloc((size_t)2 * 262144 * 16);         // 8.4 MB
    int4*           WfPK   = (int4*)alloc((size_t)32768 * 16);              // 0.5 MB
    __hip_bfloat16* Msg  = (__hip_bfloat16*)alloc((size_t)NN * 2048 * 2);   // 41 MB
    // total ~99 MB

    hipMemsetAsync(bcnt, 0, (size_t)NN * NT * 4, stream);
    hipMemsetAsync(om, 0, HD * 4, stream);
    prep_all<<<1024 + 2048 + 128 + 5000 + 625, 256, 0, stream>>>(
        Wmsg, Wih, Whh, fcW, x, edges, WmPK, WrznhPK, WfPK, abA, bcnt, bins);

    for (int s = 0; s < 4; ++s) {
        int layer = s >> 1;
        __hip_bfloat16* cur = (s & 1) ? abB : abA;
        __hip_bfloat16* nxt = (s & 1) ? abA : abB;
        const int4* Wm = WmPK + (size_t)layer * 131072;
        const int4* Wz = WrznhPK + (size_t)layer * 262144;
        const float* bm = bmsg + (size_t)layer * 2048;
        const float* bi = bih + (size_t)layer * 1536;
        const float* bh = bhh + (size_t)layer * 1536;

        // Msg = h @ Wm^T  (out 2048, K=512)
        gemm<0><<<16 * GYROWS, 256, 0, stream>>>(cur + 512, 1024, 512, Wm,
            nullptr, nullptr, Msg, 2048, nullptr);
        // inc = gather(Msg) + cnt*bm -> cur[0:512]
        gather_msum<<<NN / 4, 256, 0, stream>>>(bins, bcnt, bm, Msg, cur);
        // fused GRU GEMM -> nxt h-slot (bf16)
        gemm<1><<<16 * GYROWS, 256, 0, stream>>>(cur, 1024, 1024, Wz,
            bi, bh, nxt + 512, 1024, nullptr);
    }
    // FC + column max (final h in abA h-slot after 4 steps)
    gemm<3><<<4 * GYROWS, 256, 0, stream>>>(abA + 512, 1024, 512, WfPK,
        fcb, nullptr, nullptr, 0, om);
    writeout<<<1, 512, 0, stream>>>(om, out);
}